// Round 1
// baseline (797.597 us; speedup 1.0000x reference)
//
#include <hip/hip_runtime.h>
#include <hip/hip_bf16.h>

// DIM=768, H=4, D_H=192, R_H=4, N_EXP=6, TOPK=3, BETA=0.5, BATCH=65536
// out = z + 0.5*(delta_share + delta_auth)
// Routing is batch-independent -> fold softmax/topk/renorm/BETA into per-head
// per-expert weights c[h][e], then fold c into A: Ac[h][d][s] = c[h][e]*A[e][d][r],
// slot s = e*4 + r (24 slots). B flat is already [24][192].
// out[b, h*192+d] = z + sum_s (sum_d' z*Ac[h][d'][s]) * B[s][d]

typedef float f4 __attribute__((ext_vector_type(4)));

__global__ void dff_setup(const float* __restrict__ A,
                          const float* __restrict__ Zs,
                          const float* __restrict__ Za,
                          float* __restrict__ Ac) {
  __shared__ float c[4][6];
  const int t = threadIdx.x;
  if (t < 4) {
    const int h = t;
    float cc[6] = {0.f, 0.f, 0.f, 0.f, 0.f, 0.f};
    for (int rt = 0; rt < 2; ++rt) {
      const float* Z = rt ? Za : Zs;
      float zz[6];
      float mx = -1e30f;
      for (int e = 0; e < 6; ++e) { zz[e] = Z[h * 6 + e]; mx = fmaxf(mx, zz[e]); }
      float p[6];
      float sum = 0.f;
      for (int e = 0; e < 6; ++e) { p[e] = expf(zz[e] - mx); sum += p[e]; }
      for (int e = 0; e < 6; ++e) p[e] /= sum;
      // top-3 (ties -> lowest index, matching lax.top_k)
      bool used[6] = {false, false, false, false, false, false};
      float ws = 0.f;
      int sel[3];
      float pv[3];
      for (int k = 0; k < 3; ++k) {
        int best = -1;
        float bv = -1.f;
        for (int e = 0; e < 6; ++e)
          if (!used[e] && p[e] > bv) { bv = p[e]; best = e; }
        used[best] = true;
        sel[k] = best;
        pv[k] = bv;
        ws += bv;
      }
      const float inv = 1.f / (ws + 1e-8f);
      for (int k = 0; k < 3; ++k) cc[sel[k]] += pv[k] * inv;
    }
    for (int e = 0; e < 6; ++e) c[h][e] = 0.5f * cc[e];  // BETA folded in
  }
  __syncthreads();
  // Ac[h][d][s] = c[h][e] * A[e][d][r],  A flat: A[e*768 + d*4 + r]
  for (int idx = threadIdx.x; idx < 4 * 192 * 24; idx += blockDim.x) {
    const int h = idx / (192 * 24);
    const int rem = idx % (192 * 24);
    const int d = rem / 24;
    const int s = rem % 24;
    const int e = s >> 2, r = s & 3;
    Ac[idx] = c[h][e] * A[e * 768 + d * 4 + r];
  }
}

// One wave per block; head = blockIdx.y so ALL table addresses are
// block-uniform -> scalar s_load, table operand rides the SGPR slot of v_fma.
// Each lane owns one (row, head) 192-float segment kept fully in registers:
// z is read from HBM exactly once, out written exactly once.
__global__ __launch_bounds__(64, 2)
void dff_main(const float* __restrict__ z,
              const float* __restrict__ B,
              const float* __restrict__ Ac,
              float* __restrict__ out) {
  const int lane = threadIdx.x;            // 0..63
  const int h = blockIdx.y;                // head (block-uniform)
  const int row = blockIdx.x * 64 + lane;  // 1024*64 = 65536 exact
  const float* __restrict__ zp = z + (size_t)row * 768 + h * 192;
  float* __restrict__ op = out + (size_t)row * 768 + h * 192;
  const float* __restrict__ Ah = Ac + h * (192 * 24);

  f4 zv[48];
#pragma unroll
  for (int i = 0; i < 48; ++i)
    zv[i] = __builtin_nontemporal_load(reinterpret_cast<const f4*>(zp) + i);

  float tmp[24];
#pragma unroll
  for (int s = 0; s < 24; ++s) tmp[s] = 0.f;

  // phase 1: tmp[s] = sum_d z[d] * Ac[h][d][s]   (4608 FMAs)
#pragma unroll
  for (int i = 0; i < 48; ++i) {
#pragma unroll
    for (int s = 0; s < 24; ++s) {
      tmp[s] = fmaf(zv[i].x, Ah[(4 * i + 0) * 24 + s],
               fmaf(zv[i].y, Ah[(4 * i + 1) * 24 + s],
               fmaf(zv[i].z, Ah[(4 * i + 2) * 24 + s],
               fmaf(zv[i].w, Ah[(4 * i + 3) * 24 + s], tmp[s]))));
    }
  }

  // phase 2: out[d] = z[d] + sum_s tmp[s] * B[s][d]   (4608 FMAs)
#pragma unroll
  for (int i = 0; i < 48; ++i) {
    f4 o = zv[i];
#pragma unroll
    for (int s = 0; s < 24; ++s) {
      const float t = tmp[s];
      o.x = fmaf(t, B[s * 192 + 4 * i + 0], o.x);
      o.y = fmaf(t, B[s * 192 + 4 * i + 1], o.y);
      o.z = fmaf(t, B[s * 192 + 4 * i + 2], o.z);
      o.w = fmaf(t, B[s * 192 + 4 * i + 3], o.w);
    }
    __builtin_nontemporal_store(o, reinterpret_cast<f4*>(op) + i);
  }
}

extern "C" void kernel_launch(void* const* d_in, const int* in_sizes, int n_in,
                              void* d_out, int out_size, void* d_ws, size_t ws_size,
                              hipStream_t stream) {
  const float* z  = (const float*)d_in[0];   // [65536, 768]
  const float* A  = (const float*)d_in[1];   // [6, 192, 4]
  const float* B  = (const float*)d_in[2];   // [6, 4, 192] == [24][192]
  const float* Zs = (const float*)d_in[3];   // [4, 6]
  const float* Za = (const float*)d_in[4];   // [4, 6]
  float* out = (float*)d_out;                // [65536, 768]
  float* Ac = (float*)d_ws;                  // 4*192*24 floats = 73728 B

  dff_setup<<<1, 256, 0, stream>>>(A, Zs, Za, Ac);
  dff_main<<<dim3(1024, 4), 64, 0, stream>>>(z, B, Ac, out);
}

// Round 2
// 378.250 us; speedup vs baseline: 2.1086x; 2.1086x over previous
//
#include <hip/hip_runtime.h>
#include <hip/hip_bf16.h>

// DIM=768, H=4, D_H=192, R_H=4, N_EXP=6, TOPK=3, BETA=0.5, BATCH=65536
// Routing is batch-independent -> fold softmax/topk/renorm/BETA into per-head
// per-expert weights c[h][e], then fold c into A, stored TRANSPOSED:
//   Ac[h][s][d] = c[h][e] * A[e][d][r],  s = e*4+r (24 slots), layout [4][24][192].
// B flat is already [24][192].
// out[b, h*192+d] = z + sum_s (sum_d' z[d']*Ac[h][s][d']) * B[s][d]
//
// Main kernel: 4 lanes cooperate per (row, head). Lane q owns interleaved
// f4 chunks d0 = (4*j+q)*4, j=0..11  (48 floats -> 48 VGPRs, no spill).
// tmp[24] reduced across the 4-lane group with shfl_xor; phase 2 each lane
// writes its own 48 outputs. z read once, out written once.

typedef float f4 __attribute__((ext_vector_type(4)));

__global__ void dff_setup(const float* __restrict__ A,
                          const float* __restrict__ Zs,
                          const float* __restrict__ Za,
                          float* __restrict__ Ac) {
  __shared__ float c[4][6];
  const int t = threadIdx.x;
  if (t < 4) {
    const int h = t;
    float cc[6] = {0.f, 0.f, 0.f, 0.f, 0.f, 0.f};
    for (int rt = 0; rt < 2; ++rt) {
      const float* Z = rt ? Za : Zs;
      float zz[6];
      float mx = -1e30f;
      for (int e = 0; e < 6; ++e) { zz[e] = Z[h * 6 + e]; mx = fmaxf(mx, zz[e]); }
      float p[6];
      float sum = 0.f;
      for (int e = 0; e < 6; ++e) { p[e] = expf(zz[e] - mx); sum += p[e]; }
      for (int e = 0; e < 6; ++e) p[e] /= sum;
      // top-3 (ties -> lowest index, matching lax.top_k)
      bool used[6] = {false, false, false, false, false, false};
      float ws = 0.f;
      int sel[3];
      float pv[3];
      for (int k = 0; k < 3; ++k) {
        int best = -1;
        float bv = -1.f;
        for (int e = 0; e < 6; ++e)
          if (!used[e] && p[e] > bv) { bv = p[e]; best = e; }
        used[best] = true;
        sel[k] = best;
        pv[k] = bv;
        ws += bv;
      }
      const float inv = 1.f / (ws + 1e-8f);
      for (int k = 0; k < 3; ++k) cc[sel[k]] += pv[k] * inv;
    }
    for (int e = 0; e < 6; ++e) c[h][e] = 0.5f * cc[e];  // BETA folded in
  }
  __syncthreads();
  // Ac[h][s][d] = c[h][e] * A[e][d][r];  A flat: A[e*768 + d*4 + r]
  for (int idx = threadIdx.x; idx < 4 * 24 * 192; idx += blockDim.x) {
    const int h = idx / (24 * 192);
    const int rem = idx % (24 * 192);
    const int s = rem / 192;
    const int d = rem % 192;
    const int e = s >> 2, r = s & 3;
    Ac[idx] = c[h][e] * A[e * 768 + d * 4 + r];
  }
}

__global__ __launch_bounds__(256, 4)
void dff_main(const float* __restrict__ z,
              const float* __restrict__ B,
              const float* __restrict__ Ac,
              float* __restrict__ out) {
  const int t = threadIdx.x;               // 0..255
  const int q = t & 3;                     // quarter within (row,head) group
  const int rl = t >> 2;                   // 0..63 local row
  const int h = blockIdx.y;                // head (block-uniform)
  const int row = blockIdx.x * 64 + rl;    // 1024*64 = 65536 exact
  const float* __restrict__ zp = z + (size_t)row * 768 + h * 192;
  float* __restrict__ op = out + (size_t)row * 768 + h * 192;
  const float* __restrict__ Ah = Ac + h * (24 * 192);

  // Lane's 12 interleaved f4 chunks: f4 index 4*j + q
  f4 zv[12];
#pragma unroll
  for (int j = 0; j < 12; ++j)
    zv[j] = __builtin_nontemporal_load(reinterpret_cast<const f4*>(zp) + 4 * j + q);

  float tmp[24];
#pragma unroll
  for (int s = 0; s < 24; ++s) tmp[s] = 0.f;

  // phase 1: partial tmp[s] over this lane's 48 d-values
#pragma unroll
  for (int j = 0; j < 12; ++j) {
    const int d0 = (4 * j + q) * 4;
#pragma unroll
    for (int s = 0; s < 24; ++s) {
      const f4 a = *reinterpret_cast<const f4*>(Ah + s * 192 + d0);
      tmp[s] = fmaf(zv[j].x, a.x,
               fmaf(zv[j].y, a.y,
               fmaf(zv[j].z, a.z,
               fmaf(zv[j].w, a.w, tmp[s]))));
    }
  }

  // reduce tmp across the 4-lane group (q = lane&3)
#pragma unroll
  for (int s = 0; s < 24; ++s) {
    tmp[s] += __shfl_xor(tmp[s], 1, 64);
    tmp[s] += __shfl_xor(tmp[s], 2, 64);
  }

  // phase 2: out[d] = z[d] + sum_s tmp[s] * B[s][d] for this lane's 48 d's
#pragma unroll
  for (int j = 0; j < 12; ++j) {
    const int d0 = (4 * j + q) * 4;
    f4 o = zv[j];
#pragma unroll
    for (int s = 0; s < 24; ++s) {
      const f4 b = *reinterpret_cast<const f4*>(B + s * 192 + d0);
      const float tv = tmp[s];
      o.x = fmaf(tv, b.x, o.x);
      o.y = fmaf(tv, b.y, o.y);
      o.z = fmaf(tv, b.z, o.z);
      o.w = fmaf(tv, b.w, o.w);
    }
    __builtin_nontemporal_store(o, reinterpret_cast<f4*>(op) + 4 * j + q);
  }
}

extern "C" void kernel_launch(void* const* d_in, const int* in_sizes, int n_in,
                              void* d_out, int out_size, void* d_ws, size_t ws_size,
                              hipStream_t stream) {
  const float* z  = (const float*)d_in[0];   // [65536, 768]
  const float* A  = (const float*)d_in[1];   // [6, 192, 4]
  const float* B  = (const float*)d_in[2];   // [6, 4, 192] == [24][192]
  const float* Zs = (const float*)d_in[3];   // [4, 6]
  const float* Za = (const float*)d_in[4];   // [4, 6]
  float* out = (float*)d_out;                // [65536, 768]
  float* Ac = (float*)d_ws;                  // 4*24*192 floats = 73728 B

  dff_setup<<<1, 256, 0, stream>>>(A, Zs, Za, Ac);
  dff_main<<<dim3(1024, 4), 256, 0, stream>>>(z, B, Ac, out);
}

// Round 3
// 124.120 us; speedup vs baseline: 6.4260x; 3.0475x over previous
//
#include <hip/hip_runtime.h>
#include <hip/hip_bf16.h>

// DIM=768, H=4, D_H=192, R_H=4, N_EXP=6, TOPK=3, BETA=0.5, BATCH=65536
// Routing is batch-independent -> fold softmax/topk/renorm/BETA into per-head
// per-expert weights c[h][e], then fold c into A, stored TRANSPOSED:
//   Ac[h][s][d] = c[h][e] * A[e][d][r],  s = e*4+r (24 slots), layout [4][24][192].
// B flat is already [24][192].
// out[b, h*192+d] = z + sum_s (sum_d' z[d']*Ac[h][s][d']) * B[s][d]
//
// Main kernel: table staged in LDS (36 KB/block). 8 lanes cooperate per
// (row, head); lane q owns interleaved f4 chunks d0=(8j+q)*4, j=0..5
// (24 floats -> 24 VGPRs). tmp[24] reduced across the 8-lane group via
// shfl_xor(1,2,4). z read from HBM once, out written once, no scratch.

typedef float f4 __attribute__((ext_vector_type(4)));

__global__ void dff_setup(const float* __restrict__ A,
                          const float* __restrict__ Zs,
                          const float* __restrict__ Za,
                          float* __restrict__ Ac) {
  __shared__ float c[4][6];
  const int t = threadIdx.x;
  if (t < 4) {
    const int h = t;
    float cc[6] = {0.f, 0.f, 0.f, 0.f, 0.f, 0.f};
    for (int rt = 0; rt < 2; ++rt) {
      const float* Z = rt ? Za : Zs;
      float zz[6];
      float mx = -1e30f;
      for (int e = 0; e < 6; ++e) { zz[e] = Z[h * 6 + e]; mx = fmaxf(mx, zz[e]); }
      float p[6];
      float sum = 0.f;
      for (int e = 0; e < 6; ++e) { p[e] = expf(zz[e] - mx); sum += p[e]; }
      for (int e = 0; e < 6; ++e) p[e] /= sum;
      // top-3 (ties -> lowest index, matching lax.top_k)
      bool used[6] = {false, false, false, false, false, false};
      float ws = 0.f;
      int sel[3];
      float pv[3];
      for (int k = 0; k < 3; ++k) {
        int best = -1;
        float bv = -1.f;
        for (int e = 0; e < 6; ++e)
          if (!used[e] && p[e] > bv) { bv = p[e]; best = e; }
        used[best] = true;
        sel[k] = best;
        pv[k] = bv;
        ws += bv;
      }
      const float inv = 1.f / (ws + 1e-8f);
      for (int k = 0; k < 3; ++k) cc[sel[k]] += pv[k] * inv;
    }
    for (int e = 0; e < 6; ++e) c[h][e] = 0.5f * cc[e];  // BETA folded in
  }
  __syncthreads();
  // Ac[h][s][d] = c[h][e] * A[e][d][r];  A flat: A[e*768 + d*4 + r]
  for (int idx = threadIdx.x; idx < 4 * 24 * 192; idx += blockDim.x) {
    const int h = idx / (24 * 192);
    const int rem = idx % (24 * 192);
    const int s = rem / 192;
    const int d = rem % 192;
    const int e = s >> 2, r = s & 3;
    Ac[idx] = c[h][e] * A[e * 768 + d * 4 + r];
  }
}

__global__ __launch_bounds__(256, 4)
void dff_main(const float* __restrict__ z,
              const float* __restrict__ B,
              const float* __restrict__ Ac,
              float* __restrict__ out) {
  __shared__ float sA[24 * 192];   // Ac[h] slice
  __shared__ float sB[24 * 192];   // B

  const int t = threadIdx.x;               // 0..255
  const int q = t & 7;                     // eighth within (row,head) group
  const int rl = t >> 3;                   // 0..31 local row
  const int h = blockIdx.y;                // head (block-uniform)
  const int row = blockIdx.x * 32 + rl;    // 2048*32 = 65536 exact
  const float* __restrict__ zp = z + (size_t)row * 768 + h * 192;
  float* __restrict__ op = out + (size_t)row * 768 + h * 192;

  // Issue z loads first so HBM latency overlaps the LDS table fill.
  // Lane's 6 interleaved f4 chunks: f4 index 8*j + q  -> 24 floats.
  f4 zv[6];
#pragma unroll
  for (int j = 0; j < 6; ++j)
    zv[j] = __builtin_nontemporal_load(reinterpret_cast<const f4*>(zp) + 8 * j + q);

  // Stage table into LDS: Ac[h] (1152 f4) + B (1152 f4).
  {
    const f4* __restrict__ Ag = reinterpret_cast<const f4*>(Ac + h * (24 * 192));
    const f4* __restrict__ Bg = reinterpret_cast<const f4*>(B);
    f4* sAv = reinterpret_cast<f4*>(sA);
    f4* sBv = reinterpret_cast<f4*>(sB);
    for (int i = t; i < 1152; i += 256) {
      sAv[i] = Ag[i];
      sBv[i] = Bg[i];
    }
  }
  __syncthreads();

  float tmp[24];
#pragma unroll
  for (int s = 0; s < 24; ++s) tmp[s] = 0.f;

  // phase 1: partial tmp[s] over this lane's 24 d-values (LDS table)
#pragma unroll
  for (int j = 0; j < 6; ++j) {
    const int d0 = (8 * j + q) * 4;
#pragma unroll
    for (int s = 0; s < 24; ++s) {
      const f4 a = *reinterpret_cast<const f4*>(sA + s * 192 + d0);
      tmp[s] = fmaf(zv[j].x, a.x,
               fmaf(zv[j].y, a.y,
               fmaf(zv[j].z, a.z,
               fmaf(zv[j].w, a.w, tmp[s]))));
    }
  }

  // reduce tmp across the 8-lane group
#pragma unroll
  for (int s = 0; s < 24; ++s) {
    tmp[s] += __shfl_xor(tmp[s], 1, 64);
    tmp[s] += __shfl_xor(tmp[s], 2, 64);
    tmp[s] += __shfl_xor(tmp[s], 4, 64);
  }

  // phase 2: out[d] = z[d] + sum_s tmp[s] * B[s][d] for this lane's 24 d's
#pragma unroll
  for (int j = 0; j < 6; ++j) {
    const int d0 = (8 * j + q) * 4;
    f4 o = zv[j];
#pragma unroll
    for (int s = 0; s < 24; ++s) {
      const f4 b = *reinterpret_cast<const f4*>(sB + s * 192 + d0);
      const float tv = tmp[s];
      o.x = fmaf(tv, b.x, o.x);
      o.y = fmaf(tv, b.y, o.y);
      o.z = fmaf(tv, b.z, o.z);
      o.w = fmaf(tv, b.w, o.w);
    }
    __builtin_nontemporal_store(o, reinterpret_cast<f4*>(op) + 8 * j + q);
  }
}

extern "C" void kernel_launch(void* const* d_in, const int* in_sizes, int n_in,
                              void* d_out, int out_size, void* d_ws, size_t ws_size,
                              hipStream_t stream) {
  const float* z  = (const float*)d_in[0];   // [65536, 768]
  const float* A  = (const float*)d_in[1];   // [6, 192, 4]
  const float* B  = (const float*)d_in[2];   // [6, 4, 192] == [24][192]
  const float* Zs = (const float*)d_in[3];   // [4, 6]
  const float* Za = (const float*)d_in[4];   // [4, 6]
  float* out = (float*)d_out;                // [65536, 768]
  float* Ac = (float*)d_ws;                  // 4*24*192 floats = 73728 B

  dff_setup<<<1, 256, 0, stream>>>(A, Zs, Za, Ac);
  dff_main<<<dim3(2048, 4), 256, 0, stream>>>(z, B, Ac, out);
}